// Round 2
// baseline (439.321 us; speedup 1.0000x reference)
//
#include <hip/hip_runtime.h>
#include <stdint.h>

// Problem constants (reference: M,K,N = 8192,4096,4096)
#define M_DIM 8192
#define K_DIM 4096
#define N_DIM 4096

typedef __attribute__((ext_vector_type(4))) int v4i;

// ---------------------------------------------------------------------------
// Phase 1: pack int32 (values in [-127,127], harness-normalized from int8)
// down to int8. Each thread: 16 int32 (64 B, 4x dwordx4) -> 16 int8 (16 B).
// Memory-bound; exact truncation (two's complement).
// ---------------------------------------------------------------------------
__device__ __forceinline__ int pack4(v4i v) {
    return (int)(((uint32_t)v.x & 0xffu)
               | (((uint32_t)v.y & 0xffu) << 8)
               | (((uint32_t)v.z & 0xffu) << 16)
               | (((uint32_t)v.w & 0xffu) << 24));
}

__global__ __launch_bounds__(256) void pack_i32_to_i8(
    const int* __restrict__ src, int8_t* __restrict__ dst, int ngroups)
{
    const int g = blockIdx.x * 256 + threadIdx.x;   // one group = 16 elements
    if (g >= ngroups) return;
    const v4i* s = (const v4i*)src;
    v4i x0 = s[(size_t)g * 4 + 0];
    v4i x1 = s[(size_t)g * 4 + 1];
    v4i x2 = s[(size_t)g * 4 + 2];
    v4i x3 = s[(size_t)g * 4 + 3];
    v4i o;
    o.x = pack4(x0); o.y = pack4(x1); o.z = pack4(x2); o.w = pack4(x3);
    ((v4i*)dst)[g] = o;
}

// ---------------------------------------------------------------------------
// Async global->LDS, 16B per lane. LDS destination must be
// wave-uniform-base + lane*16 (HW constraint, learn_hip m104/m108).
// ---------------------------------------------------------------------------
__device__ __forceinline__ void gload16(const void* g, void* lds) {
    __builtin_amdgcn_global_load_lds(
        (__attribute__((address_space(1))) void*)(g),
        (__attribute__((address_space(3))) void*)(lds),
        16, 0, 0);
}

// ---------------------------------------------------------------------------
// Phase 2: 128x128 block tile, BK=64, 256 threads = 4 waves (2x2), each wave
// owns a 64x64 region as 4x4 tiles of 16x16, mfma_i32_16x16x64_i8.
// m97-style 2-barrier K-loop, global_load_lds width-16 staging.
// ---------------------------------------------------------------------------
__global__ __launch_bounds__(256) void int8_gemm_dequant(
    const int8_t* __restrict__ A,        // [M,K] int8 (packed), K contiguous
    const float*  __restrict__ scale_x,  // [M] f32
    const int8_t* __restrict__ W,        // [N,K] int8 (packed), K contiguous
    const float*  __restrict__ scale_w,  // [N] f32
    const float*  __restrict__ bias,     // [N] f32 (harness-normalized fp16)
    float*        __restrict__ out)      // [M,N] f32
{
    __shared__ __align__(16) int8_t Alds[128 * 64];   // 8 KB
    __shared__ __align__(16) int8_t Blds[128 * 64];   // 8 KB

    const int t    = threadIdx.x;          // 0..255
    const int lane = t & 63;
    const int w    = t >> 6;               // wave 0..3
    const int wm   = w >> 1;               // 0..1 (m half)
    const int wn   = w & 1;                // 0..1 (n half)

    const int m0 = blockIdx.y * 128;
    const int n0 = blockIdx.x * 128;

    // Staging: slot s = r*256 + t; row = s>>2, col-granule = s&3.
    // LDS dst = s*16 = wave-uniform + lane*16; global src is 16B within a row.
    const int row_s = t >> 2;              // 0..63 (r=0); +64 for r=1
    const int cgb   = (t & 3) * 16;        // byte offset in row

    const int8_t* Ag = A + (size_t)(m0 + row_s) * K_DIM + cgb;
    const int8_t* Bg = W + (size_t)(n0 + row_s) * K_DIM + cgb;
    int8_t* Ad = &Alds[t * 16];
    int8_t* Bd = &Blds[t * 16];

    // Fragment addressing (16x16x64 i8):
    // A: lane holds A[m=lane&15][k=(lane>>4)*16 + 0..15]  (16B ds_read_b128)
    // B: lane holds W[n=lane&15][k=(lane>>4)*16 + 0..15]  (B^T trick; any
    //    common k-permutation between A and B cancels in the dot product)
    const v4i* Alds4 = (const v4i*)Alds;
    const v4i* Blds4 = (const v4i*)Blds;
    const int rA  = wm * 64 + (lane & 15);
    const int rB  = wn * 64 + (lane & 15);
    const int cg0 = lane >> 4;             // k-granule 0..3

    v4i acc[4][4] = {};                    // [m-tile][n-tile]

    for (int k0 = 0; k0 < K_DIM; k0 += 64) {
        gload16(Ag + k0,                       Ad);
        gload16(Ag + k0 + (size_t)64 * K_DIM, Ad + 4096);
        gload16(Bg + k0,                       Bd);
        gload16(Bg + k0 + (size_t)64 * K_DIM, Bd + 4096);
        __syncthreads();

        v4i a[4], b[4];
#pragma unroll
        for (int i = 0; i < 4; ++i) a[i] = Alds4[(rA + i * 16) * 4 + cg0];
#pragma unroll
        for (int j = 0; j < 4; ++j) b[j] = Blds4[(rB + j * 16) * 4 + cg0];

#pragma unroll
        for (int i = 0; i < 4; ++i)
#pragma unroll
            for (int j = 0; j < 4; ++j)
                acc[i][j] = __builtin_amdgcn_mfma_i32_16x16x64_i8(
                    a[i], b[j], acc[i][j], 0, 0, 0);

        __syncthreads();
    }

    // Epilogue: dequant + bias, f32 out.
    // C/D layout (16x16, dtype-independent): col=lane&15, row=(lane>>4)*4+reg
    const int col = lane & 15;
    const int rq  = (lane >> 4) * 4;
    const float inv127sq = 1.0f / (127.0f * 127.0f);

    float sx[4][4];
#pragma unroll
    for (int i = 0; i < 4; ++i)
#pragma unroll
        for (int r = 0; r < 4; ++r)
            sx[i][r] = scale_x[m0 + wm * 64 + i * 16 + rq + r];

#pragma unroll
    for (int j = 0; j < 4; ++j) {
        const int n  = n0 + wn * 64 + j * 16 + col;
        const float sw = scale_w[n] * inv127sq;
        const float bf = bias[n];
#pragma unroll
        for (int i = 0; i < 4; ++i) {
            const int mrow = m0 + wm * 64 + i * 16 + rq;
#pragma unroll
            for (int r = 0; r < 4; ++r) {
                out[(size_t)(mrow + r) * N_DIM + n] =
                    (float)acc[i][j][r] * sx[i][r] * sw + bf;
            }
        }
    }
}

extern "C" void kernel_launch(void* const* d_in, const int* in_sizes, int n_in,
                              void* d_out, int out_size, void* d_ws, size_t ws_size,
                              hipStream_t stream) {
    // Harness normalization: integer inputs -> int32, fp16 -> f32.
    const int*   x_i32   = (const int*)  d_in[0];   // [M,K] as int32
    const float* scale_x = (const float*)d_in[1];   // [M] f32
    const int*   w_i32   = (const int*)  d_in[2];   // [N,K] as int32
    const float* scale_w = (const float*)d_in[3];   // [N] f32
    const float* bias    = (const float*)d_in[4];   // [N] f32 (from fp16)
    float* out = (float*)d_out;                     // [M,N] f32

    // Scratch layout: packed A8 then B8.
    int8_t* A8 = (int8_t*)d_ws;                          // 33,554,432 B
    int8_t* B8 = A8 + (size_t)M_DIM * K_DIM;             // 16,777,216 B

    const int a_groups = (M_DIM * K_DIM) / 16;           // 2,097,152
    const int b_groups = (N_DIM * K_DIM) / 16;           // 1,048,576
    pack_i32_to_i8<<<(a_groups + 255) / 256, 256, 0, stream>>>(x_i32, A8, a_groups);
    pack_i32_to_i8<<<(b_groups + 255) / 256, 256, 0, stream>>>(w_i32, B8, b_groups);

    dim3 grid(N_DIM / 128, M_DIM / 128);  // 32 x 64 = 2048 blocks
    int8_gemm_dequant<<<grid, 256, 0, stream>>>(A8, scale_x, B8, scale_w, bias, out);
}

// Round 3
// 432.614 us; speedup vs baseline: 1.0155x; 1.0155x over previous
//
#include <hip/hip_runtime.h>
#include <stdint.h>

// Problem constants (reference: M,K,N = 8192,4096,4096)
#define M_DIM 8192
#define K_DIM 4096
#define N_DIM 4096

typedef __attribute__((ext_vector_type(4))) int v4i;

// ---------------------------------------------------------------------------
// Phase 1: pack int32 (harness-normalized int8 values in [-127,127]) -> int8.
// Canonical coalescing (m13 6.29 TB/s pattern): one thread = one v4i load
// (16 B contiguous per lane) + one dword store (4 B contiguous per lane).
// A and B fused into one launch; branch is wave-uniform (group counts are
// multiples of 64).
// ---------------------------------------------------------------------------
__device__ __forceinline__ int pack4(v4i v) {
    return (int)(((uint32_t)v.x & 0xffu)
               | (((uint32_t)v.y & 0xffu) << 8)
               | (((uint32_t)v.z & 0xffu) << 16)
               | (((uint32_t)v.w & 0xffu) << 24));
}

__global__ __launch_bounds__(256) void pack_ab(
    const int* __restrict__ srcA, const int* __restrict__ srcB,
    int* __restrict__ dstA, int* __restrict__ dstB,
    int aGroups)   // v4i-groups in A
{
    int g = blockIdx.x * 256 + threadIdx.x;
    const v4i* src;
    int* dst;
    if (g < aGroups) { src = (const v4i*)srcA; dst = dstA; }
    else             { src = (const v4i*)srcB; dst = dstB; g -= aGroups; }
    dst[g] = pack4(src[g]);
}

// ---------------------------------------------------------------------------
// Async global->LDS, 16B per lane. LDS destination must be
// wave-uniform-base + lane*16 (HW constraint, learn_hip m104/m108).
// ---------------------------------------------------------------------------
__device__ __forceinline__ void gload16(const void* g, void* lds) {
    __builtin_amdgcn_global_load_lds(
        (__attribute__((address_space(1))) void*)(g),
        (__attribute__((address_space(3))) void*)(lds),
        16, 0, 0);
}

// ---------------------------------------------------------------------------
// Phase 2 (verified round 2, absmax 2.4e-4): 128x128 block tile, BK=64,
// 256 threads = 4 waves (2x2), each wave owns 64x64 as 4x4 tiles of 16x16,
// mfma_i32_16x16x64_i8. m97-style 2-barrier K-loop, global_load_lds staging.
// ---------------------------------------------------------------------------
__global__ __launch_bounds__(256) void int8_gemm_dequant(
    const int8_t* __restrict__ A,        // [M,K] int8 (packed), K contiguous
    const float*  __restrict__ scale_x,  // [M] f32
    const int8_t* __restrict__ W,        // [N,K] int8 (packed), K contiguous
    const float*  __restrict__ scale_w,  // [N] f32
    const float*  __restrict__ bias,     // [N] f32 (harness-normalized fp16)
    float*        __restrict__ out)      // [M,N] f32
{
    __shared__ __align__(16) int8_t Alds[128 * 64];   // 8 KB
    __shared__ __align__(16) int8_t Blds[128 * 64];   // 8 KB

    const int t    = threadIdx.x;          // 0..255
    const int lane = t & 63;
    const int w    = t >> 6;               // wave 0..3
    const int wm   = w >> 1;               // 0..1 (m half)
    const int wn   = w & 1;                // 0..1 (n half)

    const int m0 = blockIdx.y * 128;
    const int n0 = blockIdx.x * 128;

    // Staging: slot s = r*256 + t; row = s>>2, col-granule = s&3.
    // LDS dst = s*16 = wave-uniform + lane*16; global src is 16B within a row.
    const int row_s = t >> 2;              // 0..63 (r=0); +64 for r=1
    const int cgb   = (t & 3) * 16;        // byte offset in row

    const int8_t* Ag = A + (size_t)(m0 + row_s) * K_DIM + cgb;
    const int8_t* Bg = W + (size_t)(n0 + row_s) * K_DIM + cgb;
    int8_t* Ad = &Alds[t * 16];
    int8_t* Bd = &Blds[t * 16];

    // Fragment addressing (16x16x64 i8):
    // A: lane holds A[m=lane&15][k=(lane>>4)*16 + 0..15]  (16B ds_read_b128)
    // B: lane holds W[n=lane&15][k=(lane>>4)*16 + 0..15]
    const v4i* Alds4 = (const v4i*)Alds;
    const v4i* Blds4 = (const v4i*)Blds;
    const int rA  = wm * 64 + (lane & 15);
    const int rB  = wn * 64 + (lane & 15);
    const int cg0 = lane >> 4;             // k-granule 0..3

    v4i acc[4][4] = {};                    // [m-tile][n-tile]

    for (int k0 = 0; k0 < K_DIM; k0 += 64) {
        gload16(Ag + k0,                       Ad);
        gload16(Ag + k0 + (size_t)64 * K_DIM, Ad + 4096);
        gload16(Bg + k0,                       Bd);
        gload16(Bg + k0 + (size_t)64 * K_DIM, Bd + 4096);
        __syncthreads();

        v4i a[4], b[4];
#pragma unroll
        for (int i = 0; i < 4; ++i) a[i] = Alds4[(rA + i * 16) * 4 + cg0];
#pragma unroll
        for (int j = 0; j < 4; ++j) b[j] = Blds4[(rB + j * 16) * 4 + cg0];

#pragma unroll
        for (int i = 0; i < 4; ++i)
#pragma unroll
            for (int j = 0; j < 4; ++j)
                acc[i][j] = __builtin_amdgcn_mfma_i32_16x16x64_i8(
                    a[i], b[j], acc[i][j], 0, 0, 0);

        __syncthreads();
    }

    // Epilogue: dequant + bias, f32 out.
    // C/D layout (16x16, dtype-independent): col=lane&15, row=(lane>>4)*4+reg
    const int col = lane & 15;
    const int rq  = (lane >> 4) * 4;
    const float inv127sq = 1.0f / (127.0f * 127.0f);

    float sx[4][4];
#pragma unroll
    for (int i = 0; i < 4; ++i)
#pragma unroll
        for (int r = 0; r < 4; ++r)
            sx[i][r] = scale_x[m0 + wm * 64 + i * 16 + rq + r];

#pragma unroll
    for (int j = 0; j < 4; ++j) {
        const int n  = n0 + wn * 64 + j * 16 + col;
        const float sw = scale_w[n] * inv127sq;
        const float bf = bias[n];
#pragma unroll
        for (int i = 0; i < 4; ++i) {
            const int mrow = m0 + wm * 64 + i * 16 + rq;
#pragma unroll
            for (int r = 0; r < 4; ++r) {
                out[(size_t)(mrow + r) * N_DIM + n] =
                    (float)acc[i][j][r] * sx[i][r] * sw + bf;
            }
        }
    }
}

extern "C" void kernel_launch(void* const* d_in, const int* in_sizes, int n_in,
                              void* d_out, int out_size, void* d_ws, size_t ws_size,
                              hipStream_t stream) {
    // Harness normalization: integer inputs -> int32, fp16 -> f32.
    const int*   x_i32   = (const int*)  d_in[0];   // [M,K] as int32
    const float* scale_x = (const float*)d_in[1];   // [M] f32
    const int*   w_i32   = (const int*)  d_in[2];   // [N,K] as int32
    const float* scale_w = (const float*)d_in[3];   // [N] f32
    const float* bias    = (const float*)d_in[4];   // [N] f32 (from fp16)
    float* out = (float*)d_out;                     // [M,N] f32

    // Scratch layout: packed A8 then B8.
    int8_t* A8 = (int8_t*)d_ws;                          // 33,554,432 B
    int8_t* B8 = A8 + (size_t)M_DIM * K_DIM;             // 16,777,216 B

    const int a_groups = (M_DIM * K_DIM) / 4;            // 8,388,608 v4i groups
    const int b_groups = (N_DIM * K_DIM) / 4;            // 4,194,304
    const int total    = a_groups + b_groups;            // 12,582,912 (÷256 exact)
    pack_ab<<<total / 256, 256, 0, stream>>>(x_i32, w_i32, (int*)A8, (int*)B8,
                                             a_groups);

    dim3 grid(N_DIM / 128, M_DIM / 128);  // 32 x 64 = 2048 blocks
    int8_gemm_dequant<<<grid, 256, 0, stream>>>(A8, scale_x, B8, scale_w, bias, out);
}